// Round 10
// baseline (497.675 us; speedup 1.0000x reference)
//
#include <hip/hip_runtime.h>
#include <hip/hip_bf16.h>

// GRUCell fused cell. B=16384, d=1024, 2d=2048.
//   inp  = LN(concat(x,h); g1,b1) * dm
//   gates= inp @ Wg + bg ; r=sig(gates[:, :d]); z=sig(gates[:, d:])
//   inp2 = LN(concat(x, h*r); g2,b2) * dm
//   u    = tanh(inp2 @ Wu + bu)
//   out  = h*z + (1-z)*u
//
// R10: attack the measured LDS-read-bound ceiling (R9 arithmetic: 2x2@64x64
// waves -> 288KB LDS traffic vs 466 cyc MFMA per CU-step = 41% ceiling).
//  (a) wave tile 64x128 (block 128x256, 4 waves): reads/MFMA 512->384B,
//      ceiling -> 55%.
//  (b) stage-ahead double-buffer (T3 minimum 2-phase, m248-verified):
//      {STAGE(T+1 -> buf^1); read+MFMA(buf); __syncthreads} — staging
//      latency flies under the compute phase instead of being drained
//      immediately (R9 exposed ~900cyc/step). One barrier per K-step.
//      Race-free: buf^1's readers (iter T-1) retired ds_reads before the
//      iter-T-1 barrier (lgkmcnt before MFMA, MFMA before barrier).
// Kept: BK=32, granule-XOR swizzle pair (0 conflicts), XCD chunk swizzle
// (y-fastest), plain __syncthreads, no setprio, no manual vmcnt.
//
// ws layout (bytes):
//   [0,            8388608)  WgT  bf16 [2048][2048]  (WgT[n][k] = Wg[k][n])
//   [8388608,     12582912)  WuT  bf16 [1024][2048]
//   [12582912,    79691776)  ln   bf16 [16384][2048] (LN1 then LN2 output)
//   [79691776,   113246208)  hr   bf16 [16384][1024] (h * r)
// z (f32) staged in d_out between GEMM1 and GEMM2 (each element read only by
// the thread that overwrites it in GEMM2's epilogue).

#define BATCH 16384
#define DDIM  1024
#define TWOD  2048
#define LNEPS 1e-5f

#define GBK 32
#define NTH 256
#define BUFB 24576u   // bytes per LDS buffer: A 8KB + B 16KB

typedef __bf16 bf16x8 __attribute__((ext_vector_type(8)));
typedef float  f32x4  __attribute__((ext_vector_type(4)));
typedef unsigned short ushort4v __attribute__((ext_vector_type(4)));

__device__ __forceinline__ unsigned short f2bf(float f) {
    unsigned int u = __builtin_bit_cast(unsigned int, f);
    u = (u + 0x7FFFu + ((u >> 16) & 1u)) >> 16;   // round-to-nearest-even
    return (unsigned short)u;
}
__device__ __forceinline__ float bf2f(unsigned short s) {
    unsigned int u = ((unsigned int)s) << 16;
    return __builtin_bit_cast(float, u);
}
__device__ __forceinline__ void gload16(const void* g, void* l) {
    __builtin_amdgcn_global_load_lds((__attribute__((address_space(1))) void*)(g),
                                     (__attribute__((address_space(3))) void*)(l),
                                     16u, 0, 0);
}

// ---------------- weight transpose + f32->bf16 cast ------------------------
__global__ __launch_bounds__(256) void wtrans(const float* __restrict__ W,
                                              unsigned short* __restrict__ WT,
                                              int K, int N) {
    __shared__ float tile[32][33];
    const int k0 = blockIdx.x * 32;
    const int n0 = blockIdx.y * 32;
    const int tx = threadIdx.x & 31;
    const int ty = threadIdx.x >> 5;
#pragma unroll
    for (int p = 0; p < 32; p += 8)
        tile[p + ty][tx] = W[(size_t)(k0 + p + ty) * N + n0 + tx];
    __syncthreads();
#pragma unroll
    for (int p = 0; p < 32; p += 8)
        WT[(size_t)(n0 + p + ty) * K + k0 + tx] = f2bf(tile[tx][p + ty]);
}

// ---------------- fused LayerNorm over concat(x, second) -------------------
template <bool SECOND_BF16>
__global__ __launch_bounds__(256) void ln_kernel(const float* __restrict__ x,
                                                 const void* __restrict__ h2,
                                                 const float* __restrict__ g,
                                                 const float* __restrict__ bt,
                                                 const float* __restrict__ dm,
                                                 unsigned short* __restrict__ out) {
    const int row  = blockIdx.x;
    const int tid  = threadIdx.x;
    const int lane = tid & 63;
    const int w    = tid >> 6;

    const float4 xl = reinterpret_cast<const float4*>(x + (size_t)row * DDIM)[tid];
    float hv[4];
    if (SECOND_BF16) {
        const ushort4v hl = reinterpret_cast<const ushort4v*>(
            (const unsigned short*)h2 + (size_t)row * DDIM)[tid];
#pragma unroll
        for (int j = 0; j < 4; ++j) hv[j] = bf2f(hl[j]);
    } else {
        const float4 hl = reinterpret_cast<const float4*>(
            (const float*)h2 + (size_t)row * DDIM)[tid];
        hv[0] = hl.x; hv[1] = hl.y; hv[2] = hl.z; hv[3] = hl.w;
    }
    float xv[4] = {xl.x, xl.y, xl.z, xl.w};

    float s = 0.f, ss = 0.f;
#pragma unroll
    for (int j = 0; j < 4; ++j) { s += xv[j] + hv[j]; ss += xv[j]*xv[j] + hv[j]*hv[j]; }
#pragma unroll
    for (int o = 32; o; o >>= 1) { s += __shfl_xor(s, o); ss += __shfl_xor(ss, o); }
    __shared__ float red[8];
    if (lane == 0) { red[w] = s; red[4 + w] = ss; }
    __syncthreads();
    s  = red[0] + red[1] + red[2] + red[3];
    ss = red[4] + red[5] + red[6] + red[7];
    const float inv  = 1.0f / (float)TWOD;
    const float mu   = s * inv;
    const float var  = ss * inv - mu * mu;
    const float rstd = rsqrtf(var + LNEPS);

    {
        const float4 gv = reinterpret_cast<const float4*>(g)[tid];
        const float4 bv = reinterpret_cast<const float4*>(bt)[tid];
        const float4 dv = reinterpret_cast<const float4*>(dm)[tid];
        ushort4v pk;
        pk[0] = f2bf(((xv[0] - mu) * rstd * gv.x + bv.x) * dv.x);
        pk[1] = f2bf(((xv[1] - mu) * rstd * gv.y + bv.y) * dv.y);
        pk[2] = f2bf(((xv[2] - mu) * rstd * gv.z + bv.z) * dv.z);
        pk[3] = f2bf(((xv[3] - mu) * rstd * gv.w + bv.w) * dv.w);
        reinterpret_cast<ushort4v*>(out + (size_t)row * TWOD)[tid] = pk;
    }
    {
        const float4 gv = reinterpret_cast<const float4*>(g)[256 + tid];
        const float4 bv = reinterpret_cast<const float4*>(bt)[256 + tid];
        const float4 dv = reinterpret_cast<const float4*>(dm)[256 + tid];
        ushort4v pk;
        pk[0] = f2bf(((hv[0] - mu) * rstd * gv.x + bv.x) * dv.x);
        pk[1] = f2bf(((hv[1] - mu) * rstd * gv.y + bv.y) * dv.y);
        pk[2] = f2bf(((hv[2] - mu) * rstd * gv.z + bv.z) * dv.z);
        pk[3] = f2bf(((hv[3] - mu) * rstd * gv.w + bv.w) * dv.w);
        reinterpret_cast<ushort4v*>(out + (size_t)row * TWOD + DDIM)[tid] = pk;
    }
}

// ---------------- 128x256 / wave 64x128 / dbuf stage-ahead GEMM ------------
// A : [16384][2048] bf16 row-major (LN output)
// BT: [N][2048]     bf16 row-major (transposed weights)
// LDS per buffer: As[128][32] bf16 @0 (8KB) + Bs[256][32] bf16 @8KB (16KB).
// 2 buffers (48KB). Row = 64B = 4 granules; phys granule = logical ^
// ((row>>1)&3): stage SOURCE pre-XORed, dest linear, reads same XOR.
// Grid: 1D XCD-chunk swizzled, y(N)-fastest decode.
template <int EPI>
__global__ __launch_bounds__(NTH, 2) void gemmw(const unsigned short* __restrict__ A,
                                                const unsigned short* __restrict__ BT,
                                                const float* __restrict__ bias,
                                                const float* __restrict__ h,
                                                unsigned short* __restrict__ hr,
                                                float* __restrict__ zbuf,
                                                float* __restrict__ outp,
                                                int NYB) {
    __shared__ char sm[49152];
    const int tid  = threadIdx.x;
    const int lane = tid & 63;
    const int w    = tid >> 6;        // 0..3
    const int wm   = w >> 1;          // 0..1 (M-warp: 64 rows)
    const int wn   = w & 1;           // 0..1 (N-warp: 128 cols)
    const int q    = lane >> 4;       // 0..3 (K-chunk)
    const int r16  = lane & 15;

    // XCD-chunk swizzle (bijective: nwg % 8 == 0), y-fastest decode
    const int nwg = gridDim.x;
    const int cid = (blockIdx.x & 7) * (nwg >> 3) + (blockIdx.x >> 3);
    const size_t m0 = (size_t)(cid / NYB) * 128;
    const int    n0 = (cid % NYB) * 256;

    const unsigned short* Ag = A  + m0 * TWOD;
    const unsigned short* Bg = BT + (size_t)n0 * TWOD;

    // staging: A 512 granules (2/thread), B 1024 granules (4/thread).
    // rows rg, rg+64(,+128,+192) share swizzle parity ((row>>1)&3).
    const int rg = tid >> 2;                         // 0..63
    const int sg = (tid & 3) ^ ((rg >> 1) & 3);
    const unsigned short* aS0 = Ag + (size_t)rg * TWOD + sg * 8;
    const unsigned short* aS1 = Ag + (size_t)(rg + 64) * TWOD + sg * 8;
    const unsigned short* bS0 = Bg + (size_t)rg * TWOD + sg * 8;
    const unsigned short* bS1 = Bg + (size_t)(rg + 64) * TWOD + sg * 8;
    const unsigned short* bS2 = Bg + (size_t)(rg + 128) * TWOD + sg * 8;
    const unsigned short* bS3 = Bg + (size_t)(rg + 192) * TWOD + sg * 8;
    const unsigned wdst = (unsigned)w * 1024u;       // + lane*16 by HW

#define STAGE(dbase, T) { const int k_ = (T) * GBK; \
    gload16(aS0 + k_, sm + (dbase) + wdst); \
    gload16(aS1 + k_, sm + (dbase) + wdst + 4096u); \
    gload16(bS0 + k_, sm + (dbase) + wdst + 8192u); \
    gload16(bS1 + k_, sm + (dbase) + wdst + 12288u); \
    gload16(bS2 + k_, sm + (dbase) + wdst + 16384u); \
    gload16(bS3 + k_, sm + (dbase) + wdst + 20480u); }

    // frag reads: phys granule = q ^ ((r16>>1)&3) (row-parity trick)
    const unsigned pgo  = (unsigned)((q ^ ((r16 >> 1) & 3)) * 16);
    const unsigned arow = (unsigned)((wm * 64 + r16) * 64) + pgo;            // + i*1024
    const unsigned brow = 8192u + (unsigned)((wn * 128 + r16) * 64) + pgo;   // + n*1024

    f32x4 acc[4][8] = {};
    const int NT = TWOD / GBK;   // 64

    // prologue: stage tile 0 into buf0, full drain + barrier
    STAGE(0u, 0);
    __syncthreads();

    unsigned cur = 0u;
#pragma unroll 1
    for (int T = 0; T < NT; ++T) {
        if (T + 1 < NT) STAGE(cur ^ BUFB, T + 1);   // async; flies under MFMA
        bf16x8 af[4], bfr[8];
#pragma unroll
        for (int n = 0; n < 8; ++n)
            bfr[n] = *(const bf16x8*)(sm + cur + brow + (unsigned)n * 1024u);
#pragma unroll
        for (int i = 0; i < 4; ++i)
            af[i] = *(const bf16x8*)(sm + cur + arow + (unsigned)i * 1024u);
#pragma unroll
        for (int i = 0; i < 4; ++i)
#pragma unroll
            for (int n = 0; n < 8; ++n)
                acc[i][n] = __builtin_amdgcn_mfma_f32_16x16x32_bf16(af[i], bfr[n], acc[i][n], 0, 0, 0);
        __syncthreads();   // drains STAGE(T+1) (covered by compute), barrier
        cur ^= BUFB;
    }

    // epilogue: D col = lane&15, row = (lane>>4)*4 + reg  [verified m89/m91]
#pragma unroll
    for (int n = 0; n < 8; ++n) {
        const int col = n0 + wn * 128 + n * 16 + r16;
        const float bc = bias[col];
#pragma unroll
        for (int m = 0; m < 4; ++m) {
#pragma unroll
            for (int rg2 = 0; rg2 < 4; ++rg2) {
                const size_t row = m0 + wm * 64 + m * 16 + q * 4 + rg2;
                const float v = acc[m][n][rg2] + bc;
                if (EPI == 0) {
                    if (col < DDIM) {
                        const float rr = 1.0f / (1.0f + __expf(-v));
                        const size_t idx = row * DDIM + col;
                        hr[idx] = f2bf(h[idx] * rr);
                    } else {
                        const float zz = 1.0f / (1.0f + __expf(-v));
                        zbuf[row * DDIM + (col - DDIM)] = zz;
                    }
                } else {
                    const float u = tanhf(v);
                    const size_t idx = row * DDIM + col;
                    const float zz = zbuf[idx];
                    const float hv = h[idx];
                    outp[idx] = hv * zz + (1.0f - zz) * u;
                }
            }
        }
    }
#undef STAGE
}

// --------------------------------------------------------------------------
extern "C" void kernel_launch(void* const* d_in, const int* in_sizes, int n_in,
                              void* d_out, int out_size, void* d_ws, size_t ws_size,
                              hipStream_t stream) {
    const float* x  = (const float*)d_in[0];
    const float* h  = (const float*)d_in[1];
    const float* Wg = (const float*)d_in[2];
    const float* bg = (const float*)d_in[3];
    const float* Wu = (const float*)d_in[4];
    const float* bu = (const float*)d_in[5];
    const float* g1 = (const float*)d_in[6];
    const float* b1 = (const float*)d_in[7];
    const float* g2 = (const float*)d_in[8];
    const float* b2 = (const float*)d_in[9];
    const float* dm = (const float*)d_in[10];
    float* out = (float*)d_out;

    char* ws = (char*)d_ws;
    unsigned short* WgT = (unsigned short*)(ws);                    // 8 MB
    unsigned short* WuT = (unsigned short*)(ws + 8388608);          // 4 MB
    unsigned short* ln  = (unsigned short*)(ws + 12582912);         // 64 MB
    unsigned short* hr  = (unsigned short*)(ws + 79691776);         // 32 MB

    wtrans<<<dim3(64, 64), 256, 0, stream>>>(Wg, WgT, TWOD, TWOD);
    wtrans<<<dim3(64, 32), 256, 0, stream>>>(Wu, WuT, TWOD, DDIM);
    ln_kernel<false><<<BATCH, 256, 0, stream>>>(x, (const void*)h, g1, b1, dm, ln);
    // GEMM1: 128 M-blocks x 8 N-blocks(256) = 1024 (div 8 ok)
    gemmw<0><<<1024, NTH, 0, stream>>>(ln, WgT, bg, h, hr, out, nullptr, 8);
    ln_kernel<true><<<BATCH, 256, 0, stream>>>(x, (const void*)hr, g2, b2, dm, ln);
    // GEMM2: 128 x 4 = 512 (div 8 ok)
    gemmw<1><<<512, NTH, 0, stream>>>(ln, WuT, bu, h, nullptr, out, out, 4);
}